// Round 19
// baseline (160.483 us; speedup 1.0000x reference)
//
#include <hip/hip_runtime.h>
#include <hip/hip_bf16.h>
#include <math.h>

#define CSHIFT 9                 // 512 dsts per coarse bucket
#define TILE   4096              // edges per partition block
#define PSH    14                // padded bucket capacity = 16384 (padded fill ~12.3K)
#define PREPB  96                // prep blocks appended to k_part

using f16x8 = __attribute__((ext_vector_type(8))) _Float16;
using f16x2 = __attribute__((ext_vector_type(2))) _Float16;
using f32x4 = __attribute__((ext_vector_type(4))) float;

// ---- fp16 helpers ----
__device__ __forceinline__ unsigned pack_f16(float lo, float hi) {
    auto h = __builtin_amdgcn_cvt_pkrtz(lo, hi);
    return *(unsigned*)&h;
}
__device__ __forceinline__ f16x2 h2(unsigned u) { return *(f16x2*)&u; }

// ---- fp8 helpers (e4m3 HW converts) ----
__device__ __forceinline__ unsigned pack_fp8x4(float f0, float f1, float f2, float f3) {
    int w = 0;
    w = __builtin_amdgcn_cvt_pk_fp8_f32(f0, f1, w, false);
    w = __builtin_amdgcn_cvt_pk_fp8_f32(f2, f3, w, true);
    return (unsigned)w;
}
__device__ __forceinline__ void fp8x4_acc(unsigned v, float& a0, float& a1, float& a2, float& a3) {
    auto lo = __builtin_amdgcn_cvt_pk_f32_fp8((int)v, false);
    auto hi = __builtin_amdgcn_cvt_pk_f32_fp8((int)v, true);
    a0 += lo[0]; a1 += lo[1]; a2 += hi[0]; a3 += hi[1];
}

// ---------------- tiny cursor init (replaces 40us graph-captured memset blit) ----------------
__global__ void k_init(int* __restrict__ ccursor, int NC) {
    int i = threadIdx.x;
    if (i < NC) ccursor[i] = 0;
}

// ---------------- fused: [edge partition (relative cursors)] || [prep: wp + zero rows] ----------------
__global__ __launch_bounds__(256) void k_part(
    const int* __restrict__ src, const int* __restrict__ dst, int E,
    int* __restrict__ ccursor, int* __restrict__ pairs, int NC, int PB,
    const float* __restrict__ W1, const float* __restrict__ W2,
    unsigned short* __restrict__ wp1, unsigned short* __restrict__ wp2,
    unsigned* __restrict__ g1, unsigned* __restrict__ g2, int N)
{
    if ((int)blockIdx.x >= PB) {
        int idx = (blockIdx.x - PB) * 256 + threadIdx.x;
        if (idx < 32) {
            g1[(size_t)N * 32 + idx] = 0u;
            g2[(size_t)N * 32 + idx] = 0u;
        }
        if (idx < 16384) {   // W1: 128x128, NT=8
            int e = idx & 7, l = (idx >> 3) & 63, f = idx >> 9;
            int nt = f & 7, kt = f >> 3;
            int k = kt * 32 + (l >> 4) * 8 + e, nn = nt * 16 + (l & 15);
            _Float16 hv = (_Float16)W1[k * 128 + nn];
            wp1[idx] = *(unsigned short*)&hv;
        }
        int i2 = idx - 16384;
        if (i2 >= 0 && i2 < 8192) {  // W2: 128x64, NT=4
            int e = i2 & 7, l = (i2 >> 3) & 63, f = i2 >> 9;
            int nt = f & 3, kt = f >> 2;
            int k = kt * 32 + (l >> 4) * 8 + e, nn = nt * 16 + (l & 15);
            _Float16 hv = (_Float16)W2[k * 64 + nn];
            wp2[i2] = *(unsigned short*)&hv;
        }
        return;
    }
    __shared__ int sdst[TILE];
    __shared__ int stg[TILE];
    __shared__ unsigned char sbk[TILE];
    __shared__ int h[256], delta[256], cur[256];
    __shared__ int sa[256], sb[256];
    int t = threadIdx.x;
    int base = blockIdx.x * TILE;
    int cnt = min(TILE, E - base);

    h[t] = 0; __syncthreads();
    #pragma unroll
    for (int k = 0; k < TILE / 256; ++k) {
        int e = base + k * 256 + t;
        int d = (e < E) ? dst[e] : -1;
        sdst[k * 256 + t] = d;
        if (d >= 0) atomicAdd(&h[d >> CSHIFT], 1);
    }
    __syncthreads();
    int myc = h[t];
    int* c_ = sa; int* n_ = sb;
    c_[t] = myc; __syncthreads();
    for (int o = 1; o < 256; o <<= 1) {
        int val = c_[t] + ((t >= o) ? c_[t - o] : 0);
        n_[t] = val; __syncthreads();
        int* tmp = c_; c_ = n_; n_ = tmp;
    }
    int ex = c_[t] - myc;
    cur[t] = ex;
    int g = 0;
    if (t < NC && myc) g = atomicAdd(&ccursor[t], myc);   // relative cursor (init 0 by k_init)
    delta[t] = (t << PSH) + g - ex;
    __syncthreads();

    #pragma unroll
    for (int k = 0; k < TILE / 256; ++k) {
        int e = base + k * 256 + t;
        if (e < E) {
            int d = sdst[k * 256 + t];
            int b = d >> CSHIFT;
            int p = atomicAdd(&cur[b], 1);
            stg[p] = src[e] | ((d & 511) << 17);
            sbk[p] = (unsigned char)b;
        }
    }
    __syncthreads();
    for (int i = t; i < cnt; i += 256)
        pairs[delta[sbk[i]] + i] = stg[i];
}

// ---------------- build: degree + PADDED scan + dis + placement + pad-fill ----------------
__global__ __launch_bounds__(256) void k_build(const int* __restrict__ ccursor,
                                               const int* __restrict__ pairs,
                                               int2* __restrict__ seg,
                                               float* __restrict__ dis,
                                               int* __restrict__ csr, int N) {
    __shared__ int h[512];
    __shared__ int cur[512];
    __shared__ int sa[256], sb[256];
    int b = blockIdx.x, t = threadIdx.x;
    h[t] = 0; h[t + 256] = 0; __syncthreads();
    int beg = b << PSH, end = beg + ccursor[b];
    for (int i = beg + t; i < end; i += 256) atomicAdd(&h[pairs[i] >> 17], 1);
    __syncthreads();
    int h0 = h[2 * t], h1 = h[2 * t + 1];
    int p0 = (h0 + 15) & ~15;
    int p1 = (h1 + 15) & ~15;
    int s = p0 + p1;
    int* c_ = sa; int* n_ = sb;
    c_[t] = s; __syncthreads();
    for (int o = 1; o < 256; o <<= 1) {
        int val = c_[t] + ((t >= o) ? c_[t - o] : 0);
        n_[t] = val; __syncthreads();
        int* tmp = c_; c_ = n_; n_ = tmp;
    }
    int ex = c_[t] - s;
    int d0 = b << CSHIFT;
    int da = d0 + 2 * t, db = da + 1;
    cur[2 * t] = ex; cur[2 * t + 1] = ex + p0;
    if (da < N) { seg[da] = make_int2(beg + ex, beg + ex + p0);           dis[da] = rsqrtf((float)h0 + 1.0f); }
    if (db < N) { seg[db] = make_int2(beg + ex + p0, beg + ex + p0 + p1); dis[db] = rsqrtf((float)h1 + 1.0f); }
    for (int i = h0; i < p0; ++i) csr[beg + ex + i] = N;
    for (int i = h1; i < p1; ++i) csr[beg + ex + p0 + i] = N;
    __syncthreads();
    for (int i = beg + t; i < end; i += 256) {
        int pk = pairs[i];
        int p = atomicAdd(&cur[pk >> 17], 1);
        csr[beg + p] = pk & 0x1FFFF;
    }
}

// ---------------- MFMA GEMM layer 1 (1x16-row wave tile): g1(fp8) = (x @ W1) * dis[row] ----------------
__global__ __launch_bounds__(256) void k_gemm1(
    const float* __restrict__ A, const unsigned short* __restrict__ wp,
    const float* __restrict__ dis, unsigned* __restrict__ G, int M)
{
    constexpr int NT = 8;
    constexpr int ND = 32;

    union UW { uint4 q; f16x8 v; };
    union UA { unsigned u[4]; f16x8 v; };

    const int tid  = threadIdx.x;
    const int wv   = tid >> 6;
    const int lane = tid & 63;
    const int lm   = lane & 15;
    const int lk   = lane >> 4;
    const int m    = blockIdx.x * 64 + wv * 16 + lm;
    const int mc   = m < M ? m : (M - 1);

    f16x8 xf[4];
    {
        const float* Ar = A + (size_t)mc * 128;
        #pragma unroll
        for (int kt = 0; kt < 4; ++kt) {
            int cb = kt * 32 + lk * 8;
            float4 p = *(const float4*)(Ar + cb);
            float4 q = *(const float4*)(Ar + cb + 4);
            UA u;
            u.u[0] = pack_f16(p.x, p.y);
            u.u[1] = pack_f16(p.z, p.w);
            u.u[2] = pack_f16(q.x, q.y);
            u.u[3] = pack_f16(q.z, q.w);
            xf[kt] = u.v;
        }
    }

    f32x4 acc[NT];
    #pragma unroll
    for (int nt = 0; nt < NT; ++nt)
        #pragma unroll
        for (int r = 0; r < 4; ++r) acc[nt][r] = 0.f;

    const uint4* wpv = (const uint4*)wp;
    #pragma unroll
    for (int kt = 0; kt < 4; ++kt) {
        #pragma unroll
        for (int nt = 0; nt < NT; ++nt) {
            UW u; u.q = wpv[(kt * NT + nt) * 64 + lane];
            acc[nt] = __builtin_amdgcn_mfma_f32_16x16x32_f16(
                u.v, xf[kt], acc[nt], 0, 0, 0);
        }
    }

    if (m < M) {
        float dd = dis[m];
        unsigned* gr = G + (size_t)m * ND;
        #pragma unroll
        for (int nt = 0; nt < NT; ++nt)
            gr[nt * 4 + lk] = pack_fp8x4(acc[nt][0] * dd, acc[nt][1] * dd,
                                         acc[nt][2] * dd, acc[nt][3] * dd);
    }
}

// ---------------- agg1: half-wave per edge (4B fp8 loads), 32-edge main tier + 16-edge tier ----------------
__global__ __launch_bounds__(256) void k_agg1(
    const unsigned* __restrict__ g1, const int2* __restrict__ seg,
    const int* __restrict__ csr, const float* __restrict__ dis,
    const float* __restrict__ b1, unsigned* __restrict__ y1, int n)
{
    int wid  = (blockIdx.x * 256 + threadIdx.x) >> 6;
    int lane = threadIdx.x & 63;
    if (wid >= n) return;
    int d  = wid;
    int ll = lane & 31;
    int eh = lane >> 5;
    int2 se = seg[d];
    int beg = se.x, pend = se.y;

    float a0 = 0.f, a1 = 0.f, a2 = 0.f, a3 = 0.f;
    if (eh == 0)
        fp8x4_acc(g1[(size_t)d * 32 + ll], a0, a1, a2, a3);

    int j = beg;
    for (; j + 32 <= pend; j += 32) {
        unsigned v[16];
        #pragma unroll
        for (int k = 0; k < 16; ++k)
            v[k] = g1[(size_t)csr[j + 2 * k + eh] * 32 + ll];
        #pragma unroll
        for (int k = 0; k < 16; ++k)
            fp8x4_acc(v[k], a0, a1, a2, a3);
    }
    if (j < pend) {
        unsigned v[8];
        #pragma unroll
        for (int k = 0; k < 8; ++k)
            v[k] = g1[(size_t)csr[j + 2 * k + eh] * 32 + ll];
        #pragma unroll
        for (int k = 0; k < 8; ++k)
            fp8x4_acc(v[k], a0, a1, a2, a3);
    }

    a0 += __shfl_xor(a0, 32, 64);
    a1 += __shfl_xor(a1, 32, 64);
    a2 += __shfl_xor(a2, 32, 64);
    a3 += __shfl_xor(a3, 32, 64);

    float dd = dis[d];
    float4 bb = *(const float4*)(b1 + 4 * ll);
    float o0 = fmaxf(fmaf(dd, a0, bb.x), 0.f);
    float o1 = fmaxf(fmaf(dd, a1, bb.y), 0.f);
    float o2 = fmaxf(fmaf(dd, a2, bb.z), 0.f);
    float o3 = fmaxf(fmaf(dd, a3, bb.w), 0.f);
    if (lane < 32) {
        uint2 w;
        w.x = pack_f16(o0, o1);
        w.y = pack_f16(o2, o3);
        *((uint2*)(y1 + (size_t)d * 64) + ll) = w;
    }
}

// ---------------- MFMA GEMM layer 2: g2(fp16) = (y1 @ W2) * dis[row] ----------------
__global__ __launch_bounds__(256) void k_gemm2(
    const unsigned short* __restrict__ A, const unsigned short* __restrict__ wp,
    const float* __restrict__ dis, unsigned* __restrict__ G, int M)
{
    constexpr int NT = 4;
    constexpr int ND = 32;
    union UW { uint4 q; f16x8 v; };

    const int tid  = threadIdx.x;
    const int wv   = tid >> 6;
    const int lane = tid & 63;
    const int lm   = lane & 15;
    const int lk   = lane >> 4;
    const int m0   = blockIdx.x * 128 + wv * 32;

    f16x8 xf[2][4];
    int mrow[2];
    #pragma unroll
    for (int mt = 0; mt < 2; ++mt) {
        int m = m0 + mt * 16 + lm;
        mrow[mt] = m;
        int mc = m < M ? m : (M - 1);
        const uint4* Ar = (const uint4*)(A + (size_t)mc * 128);
        #pragma unroll
        for (int kt = 0; kt < 4; ++kt) {
            UW u; u.q = Ar[kt * 4 + lk];
            xf[mt][kt] = u.v;
        }
    }

    f32x4 acc[2][NT];
    #pragma unroll
    for (int mt = 0; mt < 2; ++mt)
        #pragma unroll
        for (int nt = 0; nt < NT; ++nt)
            #pragma unroll
            for (int r = 0; r < 4; ++r) acc[mt][nt][r] = 0.f;

    const uint4* wpv = (const uint4*)wp;
    #pragma unroll
    for (int kt = 0; kt < 4; ++kt) {
        f16x8 wf[NT];
        #pragma unroll
        for (int nt = 0; nt < NT; ++nt) {
            UW u; u.q = wpv[(kt * NT + nt) * 64 + lane];
            wf[nt] = u.v;
        }
        #pragma unroll
        for (int mt = 0; mt < 2; ++mt)
            #pragma unroll
            for (int nt = 0; nt < NT; ++nt)
                acc[mt][nt] = __builtin_amdgcn_mfma_f32_16x16x32_f16(
                    wf[nt], xf[mt][kt], acc[mt][nt], 0, 0, 0);
    }

    #pragma unroll
    for (int mt = 0; mt < 2; ++mt) {
        int m = mrow[mt];
        if (m < M) {
            float dd = dis[m];
            unsigned* gr = G + (size_t)m * ND;
            #pragma unroll
            for (int nt = 0; nt < NT; ++nt) {
                uint2 w;
                w.x = pack_f16(acc[mt][nt][0] * dd, acc[mt][nt][1] * dd);
                w.y = pack_f16(acc[mt][nt][2] * dd, acc[mt][nt][3] * dd);
                *(uint2*)(gr + nt * 8 + lk * 2) = w;
            }
        }
    }
}

// ---------------- agg2 + L2 normalize: eighth-wave per edge, quad-level f16 pairwise ----------------
__global__ __launch_bounds__(256) void k_agg2(
    const unsigned* __restrict__ g2, const int2* __restrict__ seg,
    const int* __restrict__ csr, const float* __restrict__ dis,
    const float* __restrict__ b2, float* __restrict__ out, int n)
{
    int wid  = (blockIdx.x * 256 + threadIdx.x) >> 6;
    int lane = threadIdx.x & 63;
    if (wid >= n) return;
    int d  = wid;
    int ol = lane & 7;
    int oh = lane >> 3;
    int2 se = seg[d];
    int beg = se.x, pend = se.y;

    float a0 = 0.f, a1 = 0.f, a2 = 0.f, a3 = 0.f;
    float a4 = 0.f, a5 = 0.f, a6 = 0.f, a7 = 0.f;

    int j = beg;
    for (; j + 32 <= pend; j += 32) {
        uint4 v[4];
        #pragma unroll
        for (int k = 0; k < 4; ++k) {
            int s = csr[j + 8 * k + oh];
            v[k] = *((const uint4*)(g2 + (size_t)s * 32) + ol);
        }
        f16x2 p0x = h2(v[0].x) + h2(v[1].x), p1x = h2(v[2].x) + h2(v[3].x);
        f16x2 p0y = h2(v[0].y) + h2(v[1].y), p1y = h2(v[2].y) + h2(v[3].y);
        f16x2 p0z = h2(v[0].z) + h2(v[1].z), p1z = h2(v[2].z) + h2(v[3].z);
        f16x2 p0w = h2(v[0].w) + h2(v[1].w), p1w = h2(v[2].w) + h2(v[3].w);
        f16x2 qx = p0x + p1x;
        f16x2 qy = p0y + p1y;
        f16x2 qz = p0z + p1z;
        f16x2 qw = p0w + p1w;
        a0 += (float)qx[0]; a1 += (float)qx[1];
        a2 += (float)qy[0]; a3 += (float)qy[1];
        a4 += (float)qz[0]; a5 += (float)qz[1];
        a6 += (float)qw[0]; a7 += (float)qw[1];
    }
    if (j < pend) {                       // exactly 16 remain
        uint4 v[2];
        #pragma unroll
        for (int k = 0; k < 2; ++k) {
            int s = csr[j + 8 * k + oh];
            v[k] = *((const uint4*)(g2 + (size_t)s * 32) + ol);
        }
        f16x2 s0 = h2(v[0].x) + h2(v[1].x);
        f16x2 s1 = h2(v[0].y) + h2(v[1].y);
        f16x2 s2 = h2(v[0].z) + h2(v[1].z);
        f16x2 s3 = h2(v[0].w) + h2(v[1].w);
        a0 += (float)s0[0]; a1 += (float)s0[1];
        a2 += (float)s1[0]; a3 += (float)s1[1];
        a4 += (float)s2[0]; a5 += (float)s2[1];
        a6 += (float)s3[0]; a7 += (float)s3[1];
    }

    a0 += __shfl_xor(a0, 8, 64); a0 += __shfl_xor(a0, 16, 64); a0 += __shfl_xor(a0, 32, 64);
    a1 += __shfl_xor(a1, 8, 64); a1 += __shfl_xor(a1, 16, 64); a1 += __shfl_xor(a1, 32, 64);
    a2 += __shfl_xor(a2, 8, 64); a2 += __shfl_xor(a2, 16, 64); a2 += __shfl_xor(a2, 32, 64);
    a3 += __shfl_xor(a3, 8, 64); a3 += __shfl_xor(a3, 16, 64); a3 += __shfl_xor(a3, 32, 64);
    a4 += __shfl_xor(a4, 8, 64); a4 += __shfl_xor(a4, 16, 64); a4 += __shfl_xor(a4, 32, 64);
    a5 += __shfl_xor(a5, 8, 64); a5 += __shfl_xor(a5, 16, 64); a5 += __shfl_xor(a5, 32, 64);
    a6 += __shfl_xor(a6, 8, 64); a6 += __shfl_xor(a6, 16, 64); a6 += __shfl_xor(a6, 32, 64);
    a7 += __shfl_xor(a7, 8, 64); a7 += __shfl_xor(a7, 16, 64); a7 += __shfl_xor(a7, 32, 64);

    uint4 sv = *((const uint4*)(g2 + (size_t)d * 32) + ol);
    f16x2 sx0 = h2(sv.x), sx1 = h2(sv.y), sx2 = h2(sv.z), sx3 = h2(sv.w);
    a0 += (float)sx0[0]; a1 += (float)sx0[1];
    a2 += (float)sx1[0]; a3 += (float)sx1[1];
    a4 += (float)sx2[0]; a5 += (float)sx2[1];
    a6 += (float)sx3[0]; a7 += (float)sx3[1];

    float dd = dis[d];
    float4 bb0 = *(const float4*)(b2 + 8 * ol);
    float4 bb1 = *(const float4*)(b2 + 8 * ol + 4);
    float v0 = fmaf(dd, a0, bb0.x);
    float v1 = fmaf(dd, a1, bb0.y);
    float v2 = fmaf(dd, a2, bb0.z);
    float v3 = fmaf(dd, a3, bb0.w);
    float v4 = fmaf(dd, a4, bb1.x);
    float v5 = fmaf(dd, a5, bb1.y);
    float v6 = fmaf(dd, a6, bb1.z);
    float v7 = fmaf(dd, a7, bb1.w);

    float ss = v0 * v0 + v1 * v1 + v2 * v2 + v3 * v3
             + v4 * v4 + v5 * v5 + v6 * v6 + v7 * v7;
    ss += __shfl_xor(ss, 1, 64);
    ss += __shfl_xor(ss, 2, 64);
    ss += __shfl_xor(ss, 4, 64);
    float inv = 1.0f / fmaxf(sqrtf(ss), 1e-12f);
    if (oh == 0) {
        float4 w0 = make_float4(v0 * inv, v1 * inv, v2 * inv, v3 * inv);
        float4 w1 = make_float4(v4 * inv, v5 * inv, v6 * inv, v7 * inv);
        *((float4*)(out + (size_t)d * 64 + 8 * ol))     = w0;
        *((float4*)(out + (size_t)d * 64 + 8 * ol + 4)) = w1;
    }
}

// ---------------- launcher ----------------
extern "C" void kernel_launch(void* const* d_in, const int* in_sizes, int n_in,
                              void* d_out, int out_size, void* d_ws, size_t ws_size,
                              hipStream_t stream) {
    const float* x  = (const float*)d_in[0];
    const int*   ei = (const int*)d_in[1];
    const float* W1 = (const float*)d_in[2];
    const float* b1 = (const float*)d_in[3];
    const float* W2 = (const float*)d_in[4];
    const float* b2 = (const float*)d_in[5];

    const int N = in_sizes[0] / 128;   // 100000
    const int E = in_sizes[1] / 2;     // 1600000
    const int* src = ei;
    const int* dst = ei + E;
    const int NC = (N + 511) >> CSHIFT;          // 196 coarse buckets
    const int PB = (E + TILE - 1) / TILE;        // 391 partition blocks

    char* ws = (char*)d_ws;
    size_t cur = 0;
    auto alloc = [&](size_t bytes) -> void* {
        void* p = ws + cur;
        cur += (bytes + 255) & ~(size_t)255;
        return p;
    };
    int2*           seg     = (int2*)           alloc((size_t)N * 8);
    int*            ccursor = (int*)            alloc((size_t)NC * 4);
    float*          dis     = (float*)          alloc((size_t)N * 4);
    int*            csr     = (int*)            alloc(((size_t)NC << PSH) * 4);
    int*            pairs   = (int*)            alloc(((size_t)NC << PSH) * 4);
    unsigned short* wp1     = (unsigned short*) alloc(16384 * 2);
    unsigned short* wp2     = (unsigned short*) alloc(8192 * 2);
    unsigned*       g1      = (unsigned*)       alloc((size_t)(N + 1) * 32 * 4);  // fp8x4 (+zero row)
    unsigned*       y1      = (unsigned*)       alloc((size_t)N * 64 * 4);        // fp16x2
    unsigned*       g2      = (unsigned*)       alloc((size_t)(N + 1) * 32 * 4);  // fp16x2 (+zero row)
    float*          out     = (float*)d_out;

    k_init<<<1, 256, 0, stream>>>(ccursor, NC);
    k_part<<<PB + PREPB, 256, 0, stream>>>(src, dst, E, ccursor, pairs, NC, PB,
                                           W1, W2, wp1, wp2, g1, g2, N);
    k_build<<<NC, 256, 0, stream>>>(ccursor, pairs, seg, dis, csr, N);

    // layer 1 GEMM: g1 = fp8((x @ W1) * dis)
    k_gemm1<<<(N + 63) / 64, 256, 0, stream>>>(x, wp1, dis, g1, N);
    // layer-1 aggregation (fp8 gather, fp32 accum, padded)
    k_agg1<<<(N * 64 + 255) / 256, 256, 0, stream>>>(g1, seg, csr, dis, b1, y1, N);
    // layer-2 GEMM: g2 = fp16((y1 @ W2) * dis)
    k_gemm2<<<(N + 127) / 128, 256, 0, stream>>>((const unsigned short*)y1, wp2, dis, g2, N);
    // layer-2 aggregation + L2 normalize (padded)
    k_agg2<<<(N * 64 + 255) / 256, 256, 0, stream>>>(g2, seg, csr, dis, b2, out, N);
}

// Round 20
// 158.795 us; speedup vs baseline: 1.0106x; 1.0106x over previous
//
#include <hip/hip_runtime.h>
#include <hip/hip_bf16.h>
#include <math.h>

#define CSHIFT 9                 // 512 dsts per coarse bucket
#define TILE   4096              // edges per partition block
#define PSH    14                // padded bucket capacity = 16384 (padded fill ~12.3K)
#define PREPB  96                // prep blocks appended to k_part

using f16x8 = __attribute__((ext_vector_type(8))) _Float16;
using f16x2 = __attribute__((ext_vector_type(2))) _Float16;
using f32x4 = __attribute__((ext_vector_type(4))) float;
using f32x2 = __attribute__((ext_vector_type(2))) float;

// ---- fp16 helpers ----
__device__ __forceinline__ unsigned pack_f16(float lo, float hi) {
    auto h = __builtin_amdgcn_cvt_pkrtz(lo, hi);
    return *(unsigned*)&h;
}
__device__ __forceinline__ f16x2 h2(unsigned u) { return *(f16x2*)&u; }
__device__ __forceinline__ f16x2 pshfl_xor(f16x2 a, int m) {
    float f = *(float*)&a;
    f = __shfl_xor(f, m, 64);
    return *(f16x2*)&f;
}

// ---- fp8 helpers (e4m3 HW converts) ----
__device__ __forceinline__ unsigned pack_fp8x4(float f0, float f1, float f2, float f3) {
    int w = 0;
    w = __builtin_amdgcn_cvt_pk_fp8_f32(f0, f1, w, false);
    w = __builtin_amdgcn_cvt_pk_fp8_f32(f2, f3, w, true);
    return (unsigned)w;
}
__device__ __forceinline__ void fp8x4_acc2(unsigned v, f32x2& a01, f32x2& a23) {
    a01 += __builtin_amdgcn_cvt_pk_f32_fp8((int)v, false);   // v_pk_add_f32
    a23 += __builtin_amdgcn_cvt_pk_f32_fp8((int)v, true);
}

// ---------------- tiny cursor init ----------------
__global__ void k_init(int* __restrict__ ccursor, int NC) {
    int i = threadIdx.x;
    if (i < NC) ccursor[i] = 0;
}

// ---------------- fused: [edge partition (relative cursors)] || [prep: wp + zero rows] ----------------
__global__ __launch_bounds__(256) void k_part(
    const int* __restrict__ src, const int* __restrict__ dst, int E,
    int* __restrict__ ccursor, int* __restrict__ pairs, int NC, int PB,
    const float* __restrict__ W1, const float* __restrict__ W2,
    unsigned short* __restrict__ wp1, unsigned short* __restrict__ wp2,
    unsigned* __restrict__ g1, unsigned* __restrict__ g2, int N)
{
    if ((int)blockIdx.x >= PB) {
        int idx = (blockIdx.x - PB) * 256 + threadIdx.x;
        if (idx < 32) {
            g1[(size_t)N * 32 + idx] = 0u;
            g2[(size_t)N * 32 + idx] = 0u;
        }
        if (idx < 16384) {   // W1: 128x128, NT=8
            int e = idx & 7, l = (idx >> 3) & 63, f = idx >> 9;
            int nt = f & 7, kt = f >> 3;
            int k = kt * 32 + (l >> 4) * 8 + e, nn = nt * 16 + (l & 15);
            _Float16 hv = (_Float16)W1[k * 128 + nn];
            wp1[idx] = *(unsigned short*)&hv;
        }
        int i2 = idx - 16384;
        if (i2 >= 0 && i2 < 8192) {  // W2: 128x64, NT=4
            int e = i2 & 7, l = (i2 >> 3) & 63, f = i2 >> 9;
            int nt = f & 3, kt = f >> 2;
            int k = kt * 32 + (l >> 4) * 8 + e, nn = nt * 16 + (l & 15);
            _Float16 hv = (_Float16)W2[k * 64 + nn];
            wp2[i2] = *(unsigned short*)&hv;
        }
        return;
    }
    __shared__ int sdst[TILE];
    __shared__ int stg[TILE];
    __shared__ unsigned char sbk[TILE];
    __shared__ int h[256], delta[256], cur[256];
    __shared__ int sa[256], sb[256];
    int t = threadIdx.x;
    int base = blockIdx.x * TILE;
    int cnt = min(TILE, E - base);

    h[t] = 0; __syncthreads();
    #pragma unroll
    for (int k = 0; k < TILE / 256; ++k) {
        int e = base + k * 256 + t;
        int d = (e < E) ? dst[e] : -1;
        sdst[k * 256 + t] = d;
        if (d >= 0) atomicAdd(&h[d >> CSHIFT], 1);
    }
    __syncthreads();
    int myc = h[t];
    int* c_ = sa; int* n_ = sb;
    c_[t] = myc; __syncthreads();
    for (int o = 1; o < 256; o <<= 1) {
        int val = c_[t] + ((t >= o) ? c_[t - o] : 0);
        n_[t] = val; __syncthreads();
        int* tmp = c_; c_ = n_; n_ = tmp;
    }
    int ex = c_[t] - myc;
    cur[t] = ex;
    int g = 0;
    if (t < NC && myc) g = atomicAdd(&ccursor[t], myc);
    delta[t] = (t << PSH) + g - ex;
    __syncthreads();

    #pragma unroll
    for (int k = 0; k < TILE / 256; ++k) {
        int e = base + k * 256 + t;
        if (e < E) {
            int d = sdst[k * 256 + t];
            int b = d >> CSHIFT;
            int p = atomicAdd(&cur[b], 1);
            stg[p] = src[e] | ((d & 511) << 17);
            sbk[p] = (unsigned char)b;
        }
    }
    __syncthreads();
    for (int i = t; i < cnt; i += 256)
        pairs[delta[sbk[i]] + i] = stg[i];
}

// ---------------- build: degree + PADDED scan + dis + placement + pad-fill ----------------
__global__ __launch_bounds__(256) void k_build(const int* __restrict__ ccursor,
                                               const int* __restrict__ pairs,
                                               int2* __restrict__ seg,
                                               float* __restrict__ dis,
                                               int* __restrict__ csr, int N) {
    __shared__ int h[512];
    __shared__ int cur[512];
    __shared__ int sa[256], sb[256];
    int b = blockIdx.x, t = threadIdx.x;
    h[t] = 0; h[t + 256] = 0; __syncthreads();
    int beg = b << PSH, end = beg + ccursor[b];
    for (int i = beg + t; i < end; i += 256) atomicAdd(&h[pairs[i] >> 17], 1);
    __syncthreads();
    int h0 = h[2 * t], h1 = h[2 * t + 1];
    int p0 = (h0 + 15) & ~15;
    int p1 = (h1 + 15) & ~15;
    int s = p0 + p1;
    int* c_ = sa; int* n_ = sb;
    c_[t] = s; __syncthreads();
    for (int o = 1; o < 256; o <<= 1) {
        int val = c_[t] + ((t >= o) ? c_[t - o] : 0);
        n_[t] = val; __syncthreads();
        int* tmp = c_; c_ = n_; n_ = tmp;
    }
    int ex = c_[t] - s;
    int d0 = b << CSHIFT;
    int da = d0 + 2 * t, db = da + 1;
    cur[2 * t] = ex; cur[2 * t + 1] = ex + p0;
    if (da < N) { seg[da] = make_int2(beg + ex, beg + ex + p0);           dis[da] = rsqrtf((float)h0 + 1.0f); }
    if (db < N) { seg[db] = make_int2(beg + ex + p0, beg + ex + p0 + p1); dis[db] = rsqrtf((float)h1 + 1.0f); }
    for (int i = h0; i < p0; ++i) csr[beg + ex + i] = N;
    for (int i = h1; i < p1; ++i) csr[beg + ex + p0 + i] = N;
    __syncthreads();
    for (int i = beg + t; i < end; i += 256) {
        int pk = pairs[i];
        int p = atomicAdd(&cur[pk >> 17], 1);
        csr[beg + p] = pk & 0x1FFFF;
    }
}

// ---------------- MFMA GEMM layer 1 (1x16-row wave tile): g1(fp8) = (x @ W1) * dis[row] ----------------
__global__ __launch_bounds__(256) void k_gemm1(
    const float* __restrict__ A, const unsigned short* __restrict__ wp,
    const float* __restrict__ dis, unsigned* __restrict__ G, int M)
{
    constexpr int NT = 8;
    constexpr int ND = 32;

    union UW { uint4 q; f16x8 v; };
    union UA { unsigned u[4]; f16x8 v; };

    const int tid  = threadIdx.x;
    const int wv   = tid >> 6;
    const int lane = tid & 63;
    const int lm   = lane & 15;
    const int lk   = lane >> 4;
    const int m    = blockIdx.x * 64 + wv * 16 + lm;
    const int mc   = m < M ? m : (M - 1);

    f16x8 xf[4];
    {
        const float* Ar = A + (size_t)mc * 128;
        #pragma unroll
        for (int kt = 0; kt < 4; ++kt) {
            int cb = kt * 32 + lk * 8;
            float4 p = *(const float4*)(Ar + cb);
            float4 q = *(const float4*)(Ar + cb + 4);
            UA u;
            u.u[0] = pack_f16(p.x, p.y);
            u.u[1] = pack_f16(p.z, p.w);
            u.u[2] = pack_f16(q.x, q.y);
            u.u[3] = pack_f16(q.z, q.w);
            xf[kt] = u.v;
        }
    }

    f32x4 acc[NT];
    #pragma unroll
    for (int nt = 0; nt < NT; ++nt)
        #pragma unroll
        for (int r = 0; r < 4; ++r) acc[nt][r] = 0.f;

    const uint4* wpv = (const uint4*)wp;
    #pragma unroll
    for (int kt = 0; kt < 4; ++kt) {
        #pragma unroll
        for (int nt = 0; nt < NT; ++nt) {
            UW u; u.q = wpv[(kt * NT + nt) * 64 + lane];
            acc[nt] = __builtin_amdgcn_mfma_f32_16x16x32_f16(
                u.v, xf[kt], acc[nt], 0, 0, 0);
        }
    }

    if (m < M) {
        float dd = dis[m];
        unsigned* gr = G + (size_t)m * ND;
        #pragma unroll
        for (int nt = 0; nt < NT; ++nt)
            gr[nt * 4 + lk] = pack_fp8x4(acc[nt][0] * dd, acc[nt][1] * dd,
                                         acc[nt][2] * dd, acc[nt][3] * dd);
    }
}

// ---------------- agg1: half-wave per edge, pk_f32 accum, 32/16-edge tiers ----------------
__global__ __launch_bounds__(256) void k_agg1(
    const unsigned* __restrict__ g1, const int2* __restrict__ seg,
    const int* __restrict__ csr, const float* __restrict__ dis,
    const float* __restrict__ b1, unsigned* __restrict__ y1, int n)
{
    int wid  = (blockIdx.x * 256 + threadIdx.x) >> 6;
    int lane = threadIdx.x & 63;
    if (wid >= n) return;
    int d  = wid;
    int ll = lane & 31;
    int eh = lane >> 5;
    int2 se = seg[d];
    int beg = se.x, pend = se.y;

    f32x2 a01 = {0.f, 0.f}, a23 = {0.f, 0.f};
    if (eh == 0)
        fp8x4_acc2(g1[(size_t)d * 32 + ll], a01, a23);

    int j = beg;
    for (; j + 32 <= pend; j += 32) {
        unsigned v[16];
        #pragma unroll
        for (int k = 0; k < 16; ++k)
            v[k] = g1[(size_t)csr[j + 2 * k + eh] * 32 + ll];
        #pragma unroll
        for (int k = 0; k < 16; ++k)
            fp8x4_acc2(v[k], a01, a23);
    }
    if (j < pend) {
        unsigned v[8];
        #pragma unroll
        for (int k = 0; k < 8; ++k)
            v[k] = g1[(size_t)csr[j + 2 * k + eh] * 32 + ll];
        #pragma unroll
        for (int k = 0; k < 8; ++k)
            fp8x4_acc2(v[k], a01, a23);
    }

    float a0 = a01[0], a1 = a01[1], a2 = a23[0], a3 = a23[1];
    a0 += __shfl_xor(a0, 32, 64);
    a1 += __shfl_xor(a1, 32, 64);
    a2 += __shfl_xor(a2, 32, 64);
    a3 += __shfl_xor(a3, 32, 64);

    float dd = dis[d];
    float4 bb = *(const float4*)(b1 + 4 * ll);
    float o0 = fmaxf(fmaf(dd, a0, bb.x), 0.f);
    float o1 = fmaxf(fmaf(dd, a1, bb.y), 0.f);
    float o2 = fmaxf(fmaf(dd, a2, bb.z), 0.f);
    float o3 = fmaxf(fmaf(dd, a3, bb.w), 0.f);
    if (lane < 32) {
        uint2 w;
        w.x = pack_f16(o0, o1);
        w.y = pack_f16(o2, o3);
        *((uint2*)(y1 + (size_t)d * 64) + ll) = w;
    }
}

// ---------------- MFMA GEMM layer 2: g2(fp16) = (y1 @ W2) * dis[row] ----------------
__global__ __launch_bounds__(256) void k_gemm2(
    const unsigned short* __restrict__ A, const unsigned short* __restrict__ wp,
    const float* __restrict__ dis, unsigned* __restrict__ G, int M)
{
    constexpr int NT = 4;
    constexpr int ND = 32;
    union UW { uint4 q; f16x8 v; };

    const int tid  = threadIdx.x;
    const int wv   = tid >> 6;
    const int lane = tid & 63;
    const int lm   = lane & 15;
    const int lk   = lane >> 4;
    const int m0   = blockIdx.x * 128 + wv * 32;

    f16x8 xf[2][4];
    int mrow[2];
    #pragma unroll
    for (int mt = 0; mt < 2; ++mt) {
        int m = m0 + mt * 16 + lm;
        mrow[mt] = m;
        int mc = m < M ? m : (M - 1);
        const uint4* Ar = (const uint4*)(A + (size_t)mc * 128);
        #pragma unroll
        for (int kt = 0; kt < 4; ++kt) {
            UW u; u.q = Ar[kt * 4 + lk];
            xf[mt][kt] = u.v;
        }
    }

    f32x4 acc[2][NT];
    #pragma unroll
    for (int mt = 0; mt < 2; ++mt)
        #pragma unroll
        for (int nt = 0; nt < NT; ++nt)
            #pragma unroll
            for (int r = 0; r < 4; ++r) acc[mt][nt][r] = 0.f;

    const uint4* wpv = (const uint4*)wp;
    #pragma unroll
    for (int kt = 0; kt < 4; ++kt) {
        f16x8 wf[NT];
        #pragma unroll
        for (int nt = 0; nt < NT; ++nt) {
            UW u; u.q = wpv[(kt * NT + nt) * 64 + lane];
            wf[nt] = u.v;
        }
        #pragma unroll
        for (int mt = 0; mt < 2; ++mt)
            #pragma unroll
            for (int nt = 0; nt < NT; ++nt)
                acc[mt][nt] = __builtin_amdgcn_mfma_f32_16x16x32_f16(
                    wf[nt], xf[mt][kt], acc[mt][nt], 0, 0, 0);
    }

    #pragma unroll
    for (int mt = 0; mt < 2; ++mt) {
        int m = mrow[mt];
        if (m < M) {
            float dd = dis[m];
            unsigned* gr = G + (size_t)m * ND;
            #pragma unroll
            for (int nt = 0; nt < NT; ++nt) {
                uint2 w;
                w.x = pack_f16(acc[mt][nt][0] * dd, acc[mt][nt][1] * dd);
                w.y = pack_f16(acc[mt][nt][2] * dd, acc[mt][nt][3] * dd);
                *(uint2*)(gr + nt * 8 + lk * 2) = w;
            }
        }
    }
}

// ---------------- agg2 + L2 normalize: eighth-wave per edge, packed-f16 accum + packed shfl ----------------
__global__ __launch_bounds__(256) void k_agg2(
    const unsigned* __restrict__ g2, const int2* __restrict__ seg,
    const int* __restrict__ csr, const float* __restrict__ dis,
    const float* __restrict__ b2, float* __restrict__ out, int n)
{
    int wid  = (blockIdx.x * 256 + threadIdx.x) >> 6;
    int lane = threadIdx.x & 63;
    if (wid >= n) return;
    int d  = wid;
    int ol = lane & 7;
    int oh = lane >> 3;
    int2 se = seg[d];
    int beg = se.x, pend = se.y;

    f16x2 A0 = {0, 0}, A1 = {0, 0}, A2 = {0, 0}, A3 = {0, 0};

    int j = beg;
    for (; j + 32 <= pend; j += 32) {
        uint4 v[4];
        #pragma unroll
        for (int k = 0; k < 4; ++k) {
            int s = csr[j + 8 * k + oh];
            v[k] = *((const uint4*)(g2 + (size_t)s * 32) + ol);
        }
        f16x2 p0x = h2(v[0].x) + h2(v[1].x), p1x = h2(v[2].x) + h2(v[3].x);
        f16x2 p0y = h2(v[0].y) + h2(v[1].y), p1y = h2(v[2].y) + h2(v[3].y);
        f16x2 p0z = h2(v[0].z) + h2(v[1].z), p1z = h2(v[2].z) + h2(v[3].z);
        f16x2 p0w = h2(v[0].w) + h2(v[1].w), p1w = h2(v[2].w) + h2(v[3].w);
        A0 += p0x + p1x;
        A1 += p0y + p1y;
        A2 += p0z + p1z;
        A3 += p0w + p1w;
    }
    if (j < pend) {                       // exactly 16 remain
        uint4 v[2];
        #pragma unroll
        for (int k = 0; k < 2; ++k) {
            int s = csr[j + 8 * k + oh];
            v[k] = *((const uint4*)(g2 + (size_t)s * 32) + ol);
        }
        A0 += h2(v[0].x) + h2(v[1].x);
        A1 += h2(v[0].y) + h2(v[1].y);
        A2 += h2(v[0].z) + h2(v[1].z);
        A3 += h2(v[0].w) + h2(v[1].w);
    }

    // packed cross-replica reduction (12 shfl + 12 pk_add)
    #pragma unroll
    for (int o = 8; o <= 32; o <<= 1) {
        A0 += pshfl_xor(A0, o);
        A1 += pshfl_xor(A1, o);
        A2 += pshfl_xor(A2, o);
        A3 += pshfl_xor(A3, o);
    }

    // promote + self term (fp32)
    uint4 sv = *((const uint4*)(g2 + (size_t)d * 32) + ol);
    f16x2 sx0 = h2(sv.x), sx1 = h2(sv.y), sx2 = h2(sv.z), sx3 = h2(sv.w);
    float a0 = (float)A0[0] + (float)sx0[0];
    float a1 = (float)A0[1] + (float)sx0[1];
    float a2 = (float)A1[0] + (float)sx1[0];
    float a3 = (float)A1[1] + (float)sx1[1];
    float a4 = (float)A2[0] + (float)sx2[0];
    float a5 = (float)A2[1] + (float)sx2[1];
    float a6 = (float)A3[0] + (float)sx3[0];
    float a7 = (float)A3[1] + (float)sx3[1];

    float dd = dis[d];
    float4 bb0 = *(const float4*)(b2 + 8 * ol);
    float4 bb1 = *(const float4*)(b2 + 8 * ol + 4);
    float v0 = fmaf(dd, a0, bb0.x);
    float v1 = fmaf(dd, a1, bb0.y);
    float v2 = fmaf(dd, a2, bb0.z);
    float v3 = fmaf(dd, a3, bb0.w);
    float v4 = fmaf(dd, a4, bb1.x);
    float v5 = fmaf(dd, a5, bb1.y);
    float v6 = fmaf(dd, a6, bb1.z);
    float v7 = fmaf(dd, a7, bb1.w);

    float ss = v0 * v0 + v1 * v1 + v2 * v2 + v3 * v3
             + v4 * v4 + v5 * v5 + v6 * v6 + v7 * v7;
    ss += __shfl_xor(ss, 1, 64);
    ss += __shfl_xor(ss, 2, 64);
    ss += __shfl_xor(ss, 4, 64);
    float inv = 1.0f / fmaxf(sqrtf(ss), 1e-12f);
    if (oh == 0) {
        float4 w0 = make_float4(v0 * inv, v1 * inv, v2 * inv, v3 * inv);
        float4 w1 = make_float4(v4 * inv, v5 * inv, v6 * inv, v7 * inv);
        *((float4*)(out + (size_t)d * 64 + 8 * ol))     = w0;
        *((float4*)(out + (size_t)d * 64 + 8 * ol + 4)) = w1;
    }
}

// ---------------- launcher ----------------
extern "C" void kernel_launch(void* const* d_in, const int* in_sizes, int n_in,
                              void* d_out, int out_size, void* d_ws, size_t ws_size,
                              hipStream_t stream) {
    const float* x  = (const float*)d_in[0];
    const int*   ei = (const int*)d_in[1];
    const float* W1 = (const float*)d_in[2];
    const float* b1 = (const float*)d_in[3];
    const float* W2 = (const float*)d_in[4];
    const float* b2 = (const float*)d_in[5];

    const int N = in_sizes[0] / 128;   // 100000
    const int E = in_sizes[1] / 2;     // 1600000
    const int* src = ei;
    const int* dst = ei + E;
    const int NC = (N + 511) >> CSHIFT;          // 196 coarse buckets
    const int PB = (E + TILE - 1) / TILE;        // 391 partition blocks

    char* ws = (char*)d_ws;
    size_t cur = 0;
    auto alloc = [&](size_t bytes) -> void* {
        void* p = ws + cur;
        cur += (bytes + 255) & ~(size_t)255;
        return p;
    };
    int2*           seg     = (int2*)           alloc((size_t)N * 8);
    int*            ccursor = (int*)            alloc((size_t)NC * 4);
    float*          dis     = (float*)          alloc((size_t)N * 4);
    int*            csr     = (int*)            alloc(((size_t)NC << PSH) * 4);
    int*            pairs   = (int*)            alloc(((size_t)NC << PSH) * 4);
    unsigned short* wp1     = (unsigned short*) alloc(16384 * 2);
    unsigned short* wp2     = (unsigned short*) alloc(8192 * 2);
    unsigned*       g1      = (unsigned*)       alloc((size_t)(N + 1) * 32 * 4);  // fp8x4 (+zero row)
    unsigned*       y1      = (unsigned*)       alloc((size_t)N * 64 * 4);        // fp16x2
    unsigned*       g2      = (unsigned*)       alloc((size_t)(N + 1) * 32 * 4);  // fp16x2 (+zero row)
    float*          out     = (float*)d_out;

    k_init<<<1, 256, 0, stream>>>(ccursor, NC);
    k_part<<<PB + PREPB, 256, 0, stream>>>(src, dst, E, ccursor, pairs, NC, PB,
                                           W1, W2, wp1, wp2, g1, g2, N);
    k_build<<<NC, 256, 0, stream>>>(ccursor, pairs, seg, dis, csr, N);

    // layer 1 GEMM: g1 = fp8((x @ W1) * dis)
    k_gemm1<<<(N + 63) / 64, 256, 0, stream>>>(x, wp1, dis, g1, N);
    // layer-1 aggregation (fp8 gather, pk_f32 accum, padded)
    k_agg1<<<(N * 64 + 255) / 256, 256, 0, stream>>>(g1, seg, csr, dis, b1, y1, N);
    // layer-2 GEMM: g2 = fp16((y1 @ W2) * dis)
    k_gemm2<<<(N + 127) / 128, 256, 0, stream>>>((const unsigned short*)y1, wp2, dis, g2, N);
    // layer-2 aggregation + L2 normalize (padded)
    k_agg2<<<(N * 64 + 255) / 256, 256, 0, stream>>>(g2, seg, csr, dis, b2, out, N);
}